// Round 5
// baseline (341.486 us; speedup 1.0000x reference)
//
#include <hip/hip_runtime.h>
#include <hip/hip_bf16.h>

// Problem constants (Attention_72499047957038)
#define HIDDEN 2048
#define NHEADS 32
#define NKVH   8
#define HD     64
#define BATCH  2
#define SEQ    2048
#define ROWS   (BATCH * SEQ)   // 4096
#define NQKV   3072            // 2048 Q + 512 K + 512 V
#define KCOL   2048
#define VCOL   2560

typedef __bf16 bf16x8 __attribute__((ext_vector_type(8)));
typedef __bf16 bf16x4 __attribute__((ext_vector_type(4)));
typedef float  f32x4  __attribute__((ext_vector_type(4)));
typedef short  s16x4  __attribute__((ext_vector_type(4)));
typedef short  s16x8  __attribute__((ext_vector_type(8)));

// async global->LDS, 16B per lane; LDS dest = wave-uniform base + lane*16
__device__ __forceinline__ void gl2lds16(const void* g, void* l) {
  __builtin_amdgcn_global_load_lds(
      (const __attribute__((address_space(1))) void*)g,
      (__attribute__((address_space(3))) void*)l, 16, 0, 0);
}

__device__ __forceinline__ short f2bs(float f) {
  __bf16 h = (__bf16)f;
  return __builtin_bit_cast(short, h);
}

// raw 2^x (v_exp_f32); large-negative input underflows to 0 (used for mask)
__device__ __forceinline__ float fexp2(float x) {
#if __has_builtin(__builtin_amdgcn_exp2f)
  return __builtin_amdgcn_exp2f(x);
#else
  return exp2f(x);
#endif
}

// K=16 MFMA: P (A, from S^T C-regs) x V (B). Fallback: zero-padded K=32.
__device__ __forceinline__ f32x4 mfma16(s16x4 a, s16x4 b, f32x4 c) {
#if __has_builtin(__builtin_amdgcn_mfma_f32_16x16x16bf16_1k)
  return __builtin_amdgcn_mfma_f32_16x16x16bf16_1k(a, b, c, 0, 0, 0);
#else
  s16x8 a8 = __builtin_shufflevector(a, (s16x4){0,0,0,0}, 0,1,2,3,4,5,6,7);
  s16x8 b8 = __builtin_shufflevector(b, (s16x4){0,0,0,0}, 0,1,2,3,4,5,6,7);
  a8[4]=0;a8[5]=0;a8[6]=0;a8[7]=0; b8[4]=0;b8[5]=0;b8[6]=0;b8[7]=0;
  return __builtin_amdgcn_mfma_f32_16x16x32_bf16(
      __builtin_bit_cast(bf16x8, a8), __builtin_bit_cast(bf16x8, b8), c, 0, 0, 0);
#endif
}

// ---------------------------------------------------------------------------
// prep: merged weight convert+transpose AND x fp32->bf16 convert.
// blocks [0,2560): dstW [5120][2048] = Wqkv^T | Wo^T, 128(k)x32(n) tiles:
//   coalesced 128B fp32 row reads -> LDS (bf16, +4 pad) -> 16B/lane writes,
//   256B contiguous per n-row (was 2B/lane, 64B segments: the prep bottleneck)
// blocks [2560,4608): Xb = bf16(x), 16 elems/thread
// ---------------------------------------------------------------------------
__global__ void prep(const float* __restrict__ Wq, const float* __restrict__ Wk,
                     const float* __restrict__ Wv, const float* __restrict__ Wo,
                     const float* __restrict__ x,
                     __bf16* __restrict__ dstW, __bf16* __restrict__ Xb) {
  int bid = blockIdx.x, t = threadIdx.x;
  if (bid < 2560) {
    __shared__ __bf16 tl[32][132];   // [n][k], pad 4 (stride 264B)
    int k0 = (bid & 15) * 128;
    int n0 = (bid >> 4) * 32;
    const float* src;
    int N, c0;
    if (n0 < 2048)      { src = Wq; N = 2048; c0 = n0; }
    else if (n0 < 2560) { src = Wk; N = 512;  c0 = n0 - 2048; }
    else if (n0 < 3072) { src = Wv; N = 512;  c0 = n0 - 2560; }
    else                { src = Wo; N = 2048; c0 = n0 - 3072; }
    int rr = t >> 3;          // 0..31 row within pass
    int cc = (t & 7) * 4;     // col group
#pragma unroll
    for (int pass = 0; pass < 4; ++pass) {
      int k = pass * 32 + rr;
      float4 v = *(const float4*)(src + (size_t)(k0 + k) * N + c0 + cc);
      tl[cc + 0][k] = (__bf16)v.x;
      tl[cc + 1][k] = (__bf16)v.y;
      tl[cc + 2][k] = (__bf16)v.z;
      tl[cc + 3][k] = (__bf16)v.w;
    }
    __syncthreads();
    int n = t >> 4;           // 0..15
    int ch = t & 15;          // k-chunk (8 elems = 16B)
#pragma unroll
    for (int it = 0; it < 2; ++it) {
      int nn = n + it * 16;
      s16x4 lo = *(const s16x4*)(&tl[nn][ch * 8]);
      s16x4 hi = *(const s16x4*)(&tl[nn][ch * 8 + 4]);
      s16x8 o = __builtin_shufflevector(lo, hi, 0, 1, 2, 3, 4, 5, 6, 7);
      *(s16x8*)(dstW + (size_t)(n0 + nn) * HIDDEN + k0 + ch * 8) = o;
    }
  } else {
    size_t i = (size_t)(bid - 2560) * 256 + t;   // 16 elems per thread
    const float4* s = (const float4*)(x + i * 16);
    float4 a = s[0], b = s[1], c = s[2], d = s[3];
    bf16x8 o0, o1;
    o0[0] = (__bf16)a.x; o0[1] = (__bf16)a.y; o0[2] = (__bf16)a.z; o0[3] = (__bf16)a.w;
    o0[4] = (__bf16)b.x; o0[5] = (__bf16)b.y; o0[6] = (__bf16)b.z; o0[7] = (__bf16)b.w;
    o1[0] = (__bf16)c.x; o1[1] = (__bf16)c.y; o1[2] = (__bf16)c.z; o1[3] = (__bf16)c.w;
    o1[4] = (__bf16)d.x; o1[5] = (__bf16)d.y; o1[6] = (__bf16)d.z; o1[7] = (__bf16)d.w;
    *(bf16x8*)(Xb + i * 16)     = o0;
    *(bf16x8*)(Xb + i * 16 + 8) = o1;
  }
}

// ---------------------------------------------------------------------------
// GEMM: C[M][N] = A[M][K] @ Bt[N][K]^T  (bf16 in, fp32 accum, OutT out)
// 128x128 tile, BK=64 as 2x32 panels, XCD-swizzled 1D grid.
// ROPE variant (QKV gemm): heads 0..39 rotary fused; heads 40..47 (V)
// written TRANSPOSED into Vt[(b*8+hk)*64+d][s] instead of C.
// ---------------------------------------------------------------------------
template <typename OutT, bool ROPE>
__launch_bounds__(256, 2)
__global__ void gemm_bt(const __bf16* __restrict__ A, const __bf16* __restrict__ Bt,
                        OutT* __restrict__ C, int M, int N, int K,
                        const int* __restrict__ pos_ids, __bf16* __restrict__ Vt) {
  __shared__ __bf16 As[2][128 * 32];
  __shared__ __bf16 Bs[2][128 * 32];
  int id = blockIdx.x;
  int bm = (id & 7) * 4 + ((id >> 3) & 3);
  int bn = id >> 5;
  int t = threadIdx.x;
  int wave = t >> 6, lane = t & 63, l16 = lane & 15, quad = lane >> 4;
  int wm = (wave >> 1) * 64, wn = (wave & 1) * 64;

  f32x4 acc[4][4] = {};

  int arow = t >> 2;            // 0..63
  int ac   = (t & 3) * 8;       // 0,8,16,24
  const __bf16* Ag = A  + (size_t)(bm * 128 + arow) * K + ac;
  const __bf16* Bg = Bt + (size_t)(bn * 128 + arow) * K + ac;
  int woff = wave * 512;

  for (int k0 = 0; k0 < K; k0 += 64) {
    __syncthreads();
    gl2lds16(Ag + k0,                      &As[0][woff]);
    gl2lds16(Ag + (size_t)64 * K + k0,      &As[0][2048 + woff]);
    gl2lds16(Ag + k0 + 32,                 &As[1][woff]);
    gl2lds16(Ag + (size_t)64 * K + k0 + 32, &As[1][2048 + woff]);
    gl2lds16(Bg + k0,                      &Bs[0][woff]);
    gl2lds16(Bg + (size_t)64 * K + k0,      &Bs[0][2048 + woff]);
    gl2lds16(Bg + k0 + 32,                 &Bs[1][woff]);
    gl2lds16(Bg + (size_t)64 * K + k0 + 32, &Bs[1][2048 + woff]);
    __syncthreads();

#pragma unroll
    for (int ks = 0; ks < 2; ++ks) {
      bf16x8 af[4], bfr[4];
#pragma unroll
      for (int i = 0; i < 4; ++i) {
        af[i]  = *(const bf16x8*)(&As[ks][(wm + i * 16 + l16) * 32 + quad * 8]);
        bfr[i] = *(const bf16x8*)(&Bs[ks][(wn + i * 16 + l16) * 32 + quad * 8]);
      }
#pragma unroll
      for (int i = 0; i < 4; ++i)
#pragma unroll
        for (int j = 0; j < 4; ++j)
          acc[i][j] = __builtin_amdgcn_mfma_f32_16x16x32_bf16(af[i], bfr[j], acc[i][j], 0, 0, 0);
    }
  }

  if (ROPE) {
    int headidx = bn * 2 + (wn >> 6);   // 64-col head index
    if (headidx >= 40) {
      // V head: write transposed into Vt, skip normal C write
#pragma unroll
      for (int i = 0; i < 4; ++i) {
        int srow = bm * 128 + wm + i * 16 + quad * 4;   // +r, r=0..3 same b
        int b = srow >> 11, s = srow & 2047;
#pragma unroll
        for (int j = 0; j < 4; ++j) {
          int vcol = bn * 128 + wn + j * 16 + l16 - VCOL;
          int hk = vcol >> 6, d = vcol & 63;
          bf16x4 w;
#pragma unroll
          for (int r = 0; r < 4; ++r) w[r] = (__bf16)acc[i][j][r];
          *(bf16x4*)(Vt + ((size_t)(b * NKVH + hk) * HD + d) * SEQ + s) = w;
        }
      }
      return;
    }
    // Q/K heads: rotary
    float invrev0 = __expf(-(float)l16 * 0.28782313662425574f) * 0.15915494309189535f;
    float invrev1 = __expf(-(float)(l16 + 16) * 0.28782313662425574f) * 0.15915494309189535f;
#pragma unroll
    for (int i = 0; i < 4; ++i)
#pragma unroll
      for (int r = 0; r < 4; ++r) {
        int gr = bm * 128 + wm + i * 16 + quad * 4 + r;
        float pos = (float)pos_ids[gr];
        float rv0 = pos * invrev0; rv0 -= floorf(rv0);
        float rv1 = pos * invrev1; rv1 -= floorf(rv1);
        float a0 = rv0 * 6.283185307179586f, a1 = rv1 * 6.283185307179586f;
        float s0 = __sinf(a0), c0 = __cosf(a0);
        float s1 = __sinf(a1), c1 = __cosf(a1);
        float x0 = acc[i][0][r], x2 = acc[i][2][r];
        acc[i][0][r] = x0 * c0 - x2 * s0;
        acc[i][2][r] = x2 * c0 + x0 * s0;
        float x1 = acc[i][1][r], x3 = acc[i][3][r];
        acc[i][1][r] = x1 * c1 - x3 * s1;
        acc[i][3][r] = x3 * c1 + x1 * s1;
      }
  }

#pragma unroll
  for (int i = 0; i < 4; ++i)
#pragma unroll
    for (int j = 0; j < 4; ++j)
#pragma unroll
      for (int r = 0; r < 4; ++r)
        C[(size_t)(bm * 128 + wm + i * 16 + quad * 4 + r) * N +
          (bn * 128 + wn + j * 16 + l16)] = (OutT)acc[i][j][r];
}

// ---------------------------------------------------------------------------
// Flash attention (causal, GQA), transposed-S / register-P formulation.
// ADJACENT-PAIR (as R3): block = 1 head x 128 q-rows, dual-qi every stage,
// {M,15-M} CU-balance swizzle, XCD chunk = 2 KV groups (L2-resident).
// R4 changes (resubmitted R5 after infra flake):
//  * K LDS XOR-swizzle (slot ^= (row>>1)&3): applied to per-lane GLOBAL
//    source of gl2lds (dest stays linear) and to the b128 read index ->
//    8-way bank conflict becomes 2-way (free).
//  * V LDS removed entirely: the 16 V-fragments (8B each) are loaded
//    directly from L2-resident Vt into registers each stage, issued before
//    the exp chain (~250cy cover for ~200cy L2 latency). Kills 16 ds_read
//    + 4 ds_write + pv staging per stage; LDS 32KB -> 16KB.
// ---------------------------------------------------------------------------
__launch_bounds__(256, 4)
__global__ void flash_attn(const __bf16* __restrict__ QKV, const __bf16* __restrict__ Vt,
                           __bf16* __restrict__ O) {
  int wgid = blockIdx.x + 64 * (blockIdx.y + 8 * (int)blockIdx.z);
  int xcd  = wgid & 7;          // hardware XCD (round-robin on linear id)
  int j    = wgid >> 3;         // 0..127: position within XCD's sequence
  int G    = j >> 6;            // which of this XCD's 2 KV groups
  int gid  = xcd * 2 + G;       // (b,hk) group id 0..15
  int b    = gid >> 3;
  int hk   = gid & 7;
  int r    = j & 63;            // 0..63: 4 heads x 16 M, balance-coded
  int b0   = r & 1, b5 = (r >> 5) & 1;
  int h    = hk * 4 + b0 + 2 * b5;            // query head
  int M0   = (r >> 1) & 15;
  int M    = (b0 ^ b5) ? (15 - M0) : M0;      // q-block index 0..15
  int NT   = 2 * M + 2;                       // kv-tiles (= stages)

  int t = threadIdx.x;
  int wave = t >> 6, lane = t & 63, l16 = lane & 15, quad = lane >> 4;

  __shared__ __bf16 Ks[2][2][64 * 32];   // [buf][d-half][kr][32]  16KB

  const __bf16* Kbase = QKV + (size_t)(b * SEQ) * NQKV + KCOL + hk * HD;
  const __bf16* VtB   = Vt + (size_t)(b * NKVH + hk) * HD * SEQ;

  // K staging map: row kr, SWIZZLED col (slot ^ (row>>1)&3; key dep only on
  // lane bits [3:4] since wave rows are 16-aligned)
  int kr  = wave * 16 + (lane >> 2);
  int kcs = ((lane & 3) ^ ((lane >> 3) & 3)) * 8;
  // K read swizzle key (row = nt*16+l16 -> key = (l16>>1)&3)
  int rq  = (quad ^ ((l16 >> 1) & 3)) * 8;

  // V direct-load base: fragment (nt,dt) = 4 consecutive s at one d-row
  const __bf16* vb0 = VtB + (size_t)l16 * SEQ + quad * 4;

  const s16x4 vones = { (short)0x3F80, (short)0x3F80, (short)0x3F80, (short)0x3F80 };

  // Q fragments for both q-halves, pre-scaled by (1/8)*log2(e)
  bf16x8 qfrag[2][2];   // [qi][ks]
#pragma unroll
  for (int qi = 0; qi < 2; ++qi) {
    const __bf16* qp = QKV + (size_t)(b * SEQ + M * 128 + qi * 64 + wave * 16 + l16) * NQKV
                     + h * HD + quad * 8;
    bf16x8 q0 = *(const bf16x8*)qp;
    bf16x8 q1 = *(const bf16x8*)(qp + 32);
#pragma unroll
    for (int e = 0; e < 8; ++e) {
      qfrag[qi][0][e] = (__bf16)((float)q0[e] * 0.18033688011112042f);
      qfrag[qi][1][e] = (__bf16)((float)q1[e] * 0.18033688011112042f);
    }
  }

  f32x4 lacc[2] = { {0.f,0.f,0.f,0.f}, {0.f,0.f,0.f,0.f} };
  f32x4 oacc[2][4];
#pragma unroll
  for (int qi = 0; qi < 2; ++qi)
#pragma unroll
    for (int dt = 0; dt < 4; ++dt) oacc[qi][dt] = (f32x4){0.f, 0.f, 0.f, 0.f};

  // prologue: stage K tile 0 into buf 0
  {
    const __bf16* kp = Kbase + (size_t)kr * NQKV + kcs;
    gl2lds16(kp,      &Ks[0][0][wave * 512]);
    gl2lds16(kp + 32, &Ks[0][1][wave * 512]);
  }

  for (int kt = 0; kt < NT; ++kt) {
    int buf = kt & 1;
    __syncthreads();   // prefetch of tile kt drained; buf^1 free to fill

    bool pre = (kt < NT - 1);   // also == "qi0 active" (qi0 needs kt <= 2M)
    if (pre) {
      const __bf16* kp = Kbase + (size_t)((kt + 1) * 64 + kr) * NQKV + kcs;
      gl2lds16(kp,      &Ks[buf ^ 1][0][wave * 512]);
      gl2lds16(kp + 32, &Ks[buf ^ 1][1][wave * 512]);
    }

    // ---- S^T = K Q^T : D[k=quad*4+r][q=l16], both q-halves share kf ----
    f32x4 s0[4], s1[4];
#pragma unroll
    for (int nt = 0; nt < 4; ++nt) {
      s0[nt] = (f32x4){0.f, 0.f, 0.f, 0.f};
      s1[nt] = (f32x4){0.f, 0.f, 0.f, 0.f};
    }
#pragma unroll
    for (int ks = 0; ks < 2; ++ks) {
      bf16x8 kf[4];
#pragma unroll
      for (int nt = 0; nt < 4; ++nt)
        kf[nt] = *(const bf16x8*)(&Ks[buf][ks][(nt * 16 + l16) * 32 + rq]);
#pragma unroll
      for (int nt = 0; nt < 4; ++nt)
        s1[nt] = __builtin_amdgcn_mfma_f32_16x16x32_bf16(kf[nt], qfrag[1][ks], s1[nt], 0, 0, 0);
      if (pre) {
#pragma unroll
        for (int nt = 0; nt < 4; ++nt)
          s0[nt] = __builtin_amdgcn_mfma_f32_16x16x32_bf16(kf[nt], qfrag[0][ks], s0[nt], 0, 0, 0);
      }
    }

    // ---- V fragments direct from L2 (issued before exp chain) ----
    s16x4 vf[4][4];
    {
      const __bf16* vbk = vb0 + kt * 64;
#pragma unroll
      for (int dt = 0; dt < 4; ++dt)
#pragma unroll
        for (int nt = 0; nt < 4; ++nt)
          vf[nt][dt] = *(const s16x4*)(vbk + (size_t)dt * 16 * SEQ + nt * 16);
    }

    // ---- p = exp2(s^T); pack A-frags for K=16 PV ----
    // qi0 diag at kt == NT-2; qi1 diag at kt == NT-1; else unmasked.
    s16x4 af0[4], af1[4];
    {
      int qg = wave * 16 + l16;
      if (kt == NT - 1) {
#pragma unroll
        for (int nt = 0; nt < 4; ++nt)
#pragma unroll
          for (int rr = 0; rr < 4; ++rr) {
            int kg = nt * 16 + quad * 4 + rr;
            af1[nt][rr] = f2bs(fexp2((kg > qg) ? -1e30f : s1[nt][rr]));
          }
      } else {
#pragma unroll
        for (int nt = 0; nt < 4; ++nt)
#pragma unroll
          for (int rr = 0; rr < 4; ++rr)
            af1[nt][rr] = f2bs(fexp2(s1[nt][rr]));
      }
      if (pre) {
        if (kt == NT - 2) {
#pragma unroll
          for (int nt = 0; nt < 4; ++nt)
#pragma unroll
            for (int rr = 0; rr < 4; ++rr) {
              int kg = nt * 16 + quad * 4 + rr;
              af0[nt][rr] = f2bs(fexp2((kg > qg) ? -1e30f : s0[nt][rr]));
            }
        } else {
#pragma unroll
          for (int nt = 0; nt < 4; ++nt)
#pragma unroll
            for (int rr = 0; rr < 4; ++rr)
              af0[nt][rr] = f2bs(fexp2(s0[nt][rr]));
        }
      }
    }

    // ---- O += P @ V ; row-sum += P @ 1 (both q-halves share vf) ----
#pragma unroll
    for (int nt = 0; nt < 4; ++nt) {
#pragma unroll
      for (int dt = 0; dt < 4; ++dt)
        oacc[1][dt] = mfma16(af1[nt], vf[nt][dt], oacc[1][dt]);
      lacc[1] = mfma16(af1[nt], vones, lacc[1]);
      if (pre) {
#pragma unroll
        for (int dt = 0; dt < 4; ++dt)
          oacc[0][dt] = mfma16(af0[nt], vf[nt][dt], oacc[0][dt]);
        lacc[0] = mfma16(af0[nt], vones, lacc[0]);
      }
    }
  }

  // epilogue: lacc[qi][r] is the full row-sum for q=quad*4+r — same C-layout
  // as oacc, so normalization is lane-local (no shuffles).
#pragma unroll
  for (int qi = 0; qi < 2; ++qi) {
#pragma unroll
    for (int rr = 0; rr < 4; ++rr) {
      float inv = 1.0f / lacc[qi][rr];
#pragma unroll
      for (int dt = 0; dt < 4; ++dt) {
        float o = oacc[qi][dt][rr] * inv;
        O[(size_t)(b * SEQ + M * 128 + qi * 64 + wave * 16 + quad * 4 + rr) * HIDDEN +
          h * HD + dt * 16 + l16] = (__bf16)o;
      }
    }
  }
}

// ---------------------------------------------------------------------------
extern "C" void kernel_launch(void* const* d_in, const int* in_sizes, int n_in,
                              void* d_out, int out_size, void* d_ws, size_t ws_size,
                              hipStream_t stream) {
  const float* x  = (const float*)d_in[0];
  const float* Wq = (const float*)d_in[1];
  const float* Wk = (const float*)d_in[2];
  const float* Wv = (const float*)d_in[3];
  const float* Wo = (const float*)d_in[4];
  const int* pos  = (const int*)d_in[5];

  __bf16* Wqkvt = (__bf16*)d_ws;                       // [5120][2048]: Wqkv^T | Wo^T
  __bf16* Wot   = Wqkvt + (size_t)NQKV * HIDDEN;
  __bf16* Xb    = Wot + (size_t)HIDDEN * HIDDEN;
  __bf16* QKV   = Xb + (size_t)ROWS * HIDDEN;
  __bf16* Oat   = QKV + (size_t)ROWS * NQKV;
  __bf16* Vt    = Xb;   // alias: Xb dead after QKV GEMM

  prep<<<dim3(4608), 256, 0, stream>>>(Wq, Wk, Wv, Wo, x, Wqkvt, Xb);

  gemm_bt<__bf16, true><<<dim3(768), 256, 0, stream>>>(
      Xb, Wqkvt, QKV, ROWS, NQKV, HIDDEN, pos, Vt);

  flash_attn<<<dim3(64, NKVH, BATCH), 256, 0, stream>>>(QKV, Vt, Oat);

  gemm_bt<float, false><<<dim3(512), 256, 0, stream>>>(
      Oat, Wot, (float*)d_out, ROWS, HIDDEN, HIDDEN, nullptr, nullptr);
}

// Round 6
// 266.283 us; speedup vs baseline: 1.2824x; 1.2824x over previous
//
#include <hip/hip_runtime.h>
#include <hip/hip_bf16.h>

// Problem constants (Attention_72499047957038)
#define HIDDEN 2048
#define NHEADS 32
#define NKVH   8
#define HD     64
#define BATCH  2
#define SEQ    2048
#define ROWS   (BATCH * SEQ)   // 4096
#define NQKV   3072            // 2048 Q + 512 K + 512 V
#define KCOL   2048
#define VCOL   2560

typedef __bf16 bf16x8 __attribute__((ext_vector_type(8)));
typedef __bf16 bf16x4 __attribute__((ext_vector_type(4)));
typedef float  f32x4  __attribute__((ext_vector_type(4)));
typedef short  s16x4  __attribute__((ext_vector_type(4)));
typedef short  s16x8  __attribute__((ext_vector_type(8)));

// async global->LDS, 16B per lane; LDS dest = wave-uniform base + lane*16
__device__ __forceinline__ void gl2lds16(const void* g, void* l) {
  __builtin_amdgcn_global_load_lds(
      (const __attribute__((address_space(1))) void*)g,
      (__attribute__((address_space(3))) void*)l, 16, 0, 0);
}

__device__ __forceinline__ short f2bs(float f) {
  __bf16 h = (__bf16)f;
  return __builtin_bit_cast(short, h);
}

// raw 2^x (v_exp_f32); large-negative input underflows to 0 (used for mask)
__device__ __forceinline__ float fexp2(float x) {
#if __has_builtin(__builtin_amdgcn_exp2f)
  return __builtin_amdgcn_exp2f(x);
#else
  return exp2f(x);
#endif
}

// K=16 MFMA: P (A, from S^T C-regs) x V (B). Fallback: zero-padded K=32.
__device__ __forceinline__ f32x4 mfma16(s16x4 a, s16x4 b, f32x4 c) {
#if __has_builtin(__builtin_amdgcn_mfma_f32_16x16x16bf16_1k)
  return __builtin_amdgcn_mfma_f32_16x16x16bf16_1k(a, b, c, 0, 0, 0);
#else
  s16x8 a8 = __builtin_shufflevector(a, (s16x4){0,0,0,0}, 0,1,2,3,4,5,6,7);
  s16x8 b8 = __builtin_shufflevector(b, (s16x4){0,0,0,0}, 0,1,2,3,4,5,6,7);
  a8[4]=0;a8[5]=0;a8[6]=0;a8[7]=0; b8[4]=0;b8[5]=0;b8[6]=0;b8[7]=0;
  return __builtin_amdgcn_mfma_f32_16x16x32_bf16(
      __builtin_bit_cast(bf16x8, a8), __builtin_bit_cast(bf16x8, b8), c, 0, 0, 0);
#endif
}

// ---------------------------------------------------------------------------
// prep: merged weight convert+transpose AND x fp32->bf16 convert.
// blocks [0,2560): dstW [5120][2048] = Wqkv^T | Wo^T, 128(k)x32(n) tiles:
//   coalesced 128B fp32 row reads -> LDS (bf16, +4 pad) -> 16B/lane writes
// blocks [2560,4608): Xb = bf16(x), 16 elems/thread
// ---------------------------------------------------------------------------
__global__ void prep(const float* __restrict__ Wq, const float* __restrict__ Wk,
                     const float* __restrict__ Wv, const float* __restrict__ Wo,
                     const float* __restrict__ x,
                     __bf16* __restrict__ dstW, __bf16* __restrict__ Xb) {
  int bid = blockIdx.x, t = threadIdx.x;
  if (bid < 2560) {
    __shared__ __bf16 tl[32][132];   // [n][k], pad 4 (stride 264B)
    int k0 = (bid & 15) * 128;
    int n0 = (bid >> 4) * 32;
    const float* src;
    int N, c0;
    if (n0 < 2048)      { src = Wq; N = 2048; c0 = n0; }
    else if (n0 < 2560) { src = Wk; N = 512;  c0 = n0 - 2048; }
    else if (n0 < 3072) { src = Wv; N = 512;  c0 = n0 - 2560; }
    else                { src = Wo; N = 2048; c0 = n0 - 3072; }
    int rr = t >> 3;          // 0..31 row within pass
    int cc = (t & 7) * 4;     // col group
#pragma unroll
    for (int pass = 0; pass < 4; ++pass) {
      int k = pass * 32 + rr;
      float4 v = *(const float4*)(src + (size_t)(k0 + k) * N + c0 + cc);
      tl[cc + 0][k] = (__bf16)v.x;
      tl[cc + 1][k] = (__bf16)v.y;
      tl[cc + 2][k] = (__bf16)v.z;
      tl[cc + 3][k] = (__bf16)v.w;
    }
    __syncthreads();
    int n = t >> 4;           // 0..15
    int ch = t & 15;          // k-chunk (8 elems = 16B)
#pragma unroll
    for (int it = 0; it < 2; ++it) {
      int nn = n + it * 16;
      s16x4 lo = *(const s16x4*)(&tl[nn][ch * 8]);
      s16x4 hi = *(const s16x4*)(&tl[nn][ch * 8 + 4]);
      s16x8 o = __builtin_shufflevector(lo, hi, 0, 1, 2, 3, 4, 5, 6, 7);
      *(s16x8*)(dstW + (size_t)(n0 + nn) * HIDDEN + k0 + ch * 8) = o;
    }
  } else {
    size_t i = (size_t)(bid - 2560) * 256 + t;   // 16 elems per thread
    const float4* s = (const float4*)(x + i * 16);
    float4 a = s[0], b = s[1], c = s[2], d = s[3];
    bf16x8 o0, o1;
    o0[0] = (__bf16)a.x; o0[1] = (__bf16)a.y; o0[2] = (__bf16)a.z; o0[3] = (__bf16)a.w;
    o0[4] = (__bf16)b.x; o0[5] = (__bf16)b.y; o0[6] = (__bf16)b.z; o0[7] = (__bf16)b.w;
    o1[0] = (__bf16)c.x; o1[1] = (__bf16)c.y; o1[2] = (__bf16)c.z; o1[3] = (__bf16)c.w;
    o1[4] = (__bf16)d.x; o1[5] = (__bf16)d.y; o1[6] = (__bf16)d.z; o1[7] = (__bf16)d.w;
    *(bf16x8*)(Xb + i * 16)     = o0;
    *(bf16x8*)(Xb + i * 16 + 8) = o1;
  }
}

// ---------------------------------------------------------------------------
// GEMM: C[M][N] = A[M][K] @ Bt[N][K]^T  (bf16 in, fp32 accum, OutT out)
// 128x128 tile, BK=64 as 2x32 panels, XCD-swizzled 1D grid.
// ROPE variant (QKV gemm): heads 0..39 rotary fused; heads 40..47 (V)
// written TRANSPOSED into Vt[(b*8+hk)*64+d][s] instead of C.
// ---------------------------------------------------------------------------
template <typename OutT, bool ROPE>
__launch_bounds__(256, 2)
__global__ void gemm_bt(const __bf16* __restrict__ A, const __bf16* __restrict__ Bt,
                        OutT* __restrict__ C, int M, int N, int K,
                        const int* __restrict__ pos_ids, __bf16* __restrict__ Vt) {
  __shared__ __bf16 As[2][128 * 32];
  __shared__ __bf16 Bs[2][128 * 32];
  int id = blockIdx.x;
  int bm = (id & 7) * 4 + ((id >> 3) & 3);
  int bn = id >> 5;
  int t = threadIdx.x;
  int wave = t >> 6, lane = t & 63, l16 = lane & 15, quad = lane >> 4;
  int wm = (wave >> 1) * 64, wn = (wave & 1) * 64;

  f32x4 acc[4][4] = {};

  int arow = t >> 2;            // 0..63
  int ac   = (t & 3) * 8;       // 0,8,16,24
  const __bf16* Ag = A  + (size_t)(bm * 128 + arow) * K + ac;
  const __bf16* Bg = Bt + (size_t)(bn * 128 + arow) * K + ac;
  int woff = wave * 512;

  for (int k0 = 0; k0 < K; k0 += 64) {
    __syncthreads();
    gl2lds16(Ag + k0,                      &As[0][woff]);
    gl2lds16(Ag + (size_t)64 * K + k0,      &As[0][2048 + woff]);
    gl2lds16(Ag + k0 + 32,                 &As[1][woff]);
    gl2lds16(Ag + (size_t)64 * K + k0 + 32, &As[1][2048 + woff]);
    gl2lds16(Bg + k0,                      &Bs[0][woff]);
    gl2lds16(Bg + (size_t)64 * K + k0,      &Bs[0][2048 + woff]);
    gl2lds16(Bg + k0 + 32,                 &Bs[1][woff]);
    gl2lds16(Bg + (size_t)64 * K + k0 + 32, &Bs[1][2048 + woff]);
    __syncthreads();

#pragma unroll
    for (int ks = 0; ks < 2; ++ks) {
      bf16x8 af[4], bfr[4];
#pragma unroll
      for (int i = 0; i < 4; ++i) {
        af[i]  = *(const bf16x8*)(&As[ks][(wm + i * 16 + l16) * 32 + quad * 8]);
        bfr[i] = *(const bf16x8*)(&Bs[ks][(wn + i * 16 + l16) * 32 + quad * 8]);
      }
#pragma unroll
      for (int i = 0; i < 4; ++i)
#pragma unroll
        for (int j = 0; j < 4; ++j)
          acc[i][j] = __builtin_amdgcn_mfma_f32_16x16x32_bf16(af[i], bfr[j], acc[i][j], 0, 0, 0);
    }
  }

  if (ROPE) {
    int headidx = bn * 2 + (wn >> 6);   // 64-col head index
    if (headidx >= 40) {
      // V head: write transposed into Vt, skip normal C write
#pragma unroll
      for (int i = 0; i < 4; ++i) {
        int srow = bm * 128 + wm + i * 16 + quad * 4;   // +r, r=0..3 same b
        int b = srow >> 11, s = srow & 2047;
#pragma unroll
        for (int j = 0; j < 4; ++j) {
          int vcol = bn * 128 + wn + j * 16 + l16 - VCOL;
          int hk = vcol >> 6, d = vcol & 63;
          bf16x4 w;
#pragma unroll
          for (int r = 0; r < 4; ++r) w[r] = (__bf16)acc[i][j][r];
          *(bf16x4*)(Vt + ((size_t)(b * NKVH + hk) * HD + d) * SEQ + s) = w;
        }
      }
      return;
    }
    // Q/K heads: rotary
    float invrev0 = __expf(-(float)l16 * 0.28782313662425574f) * 0.15915494309189535f;
    float invrev1 = __expf(-(float)(l16 + 16) * 0.28782313662425574f) * 0.15915494309189535f;
#pragma unroll
    for (int i = 0; i < 4; ++i)
#pragma unroll
      for (int r = 0; r < 4; ++r) {
        int gr = bm * 128 + wm + i * 16 + quad * 4 + r;
        float pos = (float)pos_ids[gr];
        float rv0 = pos * invrev0; rv0 -= floorf(rv0);
        float rv1 = pos * invrev1; rv1 -= floorf(rv1);
        float a0 = rv0 * 6.283185307179586f, a1 = rv1 * 6.283185307179586f;
        float s0 = __sinf(a0), c0 = __cosf(a0);
        float s1 = __sinf(a1), c1 = __cosf(a1);
        float x0 = acc[i][0][r], x2 = acc[i][2][r];
        acc[i][0][r] = x0 * c0 - x2 * s0;
        acc[i][2][r] = x2 * c0 + x0 * s0;
        float x1 = acc[i][1][r], x3 = acc[i][3][r];
        acc[i][1][r] = x1 * c1 - x3 * s1;
        acc[i][3][r] = x3 * c1 + x1 * s1;
      }
  }

#pragma unroll
  for (int i = 0; i < 4; ++i)
#pragma unroll
    for (int j = 0; j < 4; ++j)
#pragma unroll
      for (int r = 0; r < 4; ++r)
        C[(size_t)(bm * 128 + wm + i * 16 + quad * 4 + r) * N +
          (bn * 128 + wn + j * 16 + l16)] = (OutT)acc[i][j][r];
}

// ---------------------------------------------------------------------------
// Flash attention (causal, GQA), transposed-S / register-P formulation.
// ADJACENT-PAIR (as R3): block = 1 head x 128 q-rows, dual-qi every stage,
// {M,15-M} CU-balance swizzle, XCD chunk = 2 KV groups (L2-resident).
// R6 = R3's V-through-LDS (deferred ds_write, reg prefetch: proven 62us)
//      + R5's K source-swizzle (conflicts -> 0, verified)
//      + V XOR-swizzle col' = d ^ 4*((s4>>2)&3) on BOTH write & read:
//        per-16-lane phase groups all 3 LDS access patterns now hit 16
//        distinct 2-bank windows -> conflict-free (R3's 5.57M was K reads
//        8-way + V writes 4-way).
// (R5's V-direct-from-L2 reverted: 16-row scatter per instr made the
//  vector-memory pipe the serial resource -> 140us.)
// ---------------------------------------------------------------------------
__launch_bounds__(256, 4)
__global__ void flash_attn(const __bf16* __restrict__ QKV, const __bf16* __restrict__ Vt,
                           __bf16* __restrict__ O) {
  int wgid = blockIdx.x + 64 * (blockIdx.y + 8 * (int)blockIdx.z);
  int xcd  = wgid & 7;          // hardware XCD (round-robin on linear id)
  int j    = wgid >> 3;         // 0..127: position within XCD's sequence
  int G    = j >> 6;            // which of this XCD's 2 KV groups
  int gid  = xcd * 2 + G;       // (b,hk) group id 0..15
  int b    = gid >> 3;
  int hk   = gid & 7;
  int r    = j & 63;            // 0..63: 4 heads x 16 M, balance-coded
  int b0   = r & 1, b5 = (r >> 5) & 1;
  int h    = hk * 4 + b0 + 2 * b5;            // query head
  int M0   = (r >> 1) & 15;
  int M    = (b0 ^ b5) ? (15 - M0) : M0;      // q-block index 0..15
  int NT   = 2 * M + 2;                       // kv-tiles (= stages)

  int t = threadIdx.x;
  int wave = t >> 6, lane = t & 63, l16 = lane & 15, quad = lane >> 4;

  __shared__ __bf16 Ks[2][2][64 * 32];   // [buf][d-half][kr][32]  16KB
  __shared__ __bf16 Vs[2][4096];         // [buf][s4][colswz][4]   16KB

  const __bf16* Kbase = QKV + (size_t)(b * SEQ) * NQKV + KCOL + hk * HD;
  const __bf16* VtB   = Vt + (size_t)(b * NKVH + hk) * HD * SEQ;

  // K staging: row kr, SWIZZLED global col chunk (slot ^ (row>>1)&3)
  int kr  = wave * 16 + (lane >> 2);
  int kcs = ((lane & 3) ^ ((lane >> 3) & 3)) * 8;
  // K read: LDS slot quad ^ ((row>>1)&3), row = nt*16+l16
  int rq  = (quad ^ ((l16 >> 1) & 3)) * 8;

  // V staging maps (per wave: rows wave*16..+15, 16 s per lane)
  int vd   = kr;                       // Vt d-row 0..63
  int vsc  = (lane & 3) * 16;          // s-chunk start
  int vs4w = (lane & 3) * 4;           // first s4 this lane writes
  int vcw4 = (vd ^ (4 * (lane & 3))) * 4;   // swizzled col*4 for writes
                                            // (key = (s4>>2)&3 = lane&3 for all 4 writes)

  const s16x4 vones = { (short)0x3F80, (short)0x3F80, (short)0x3F80, (short)0x3F80 };

  // Q fragments for both q-halves, pre-scaled by (1/8)*log2(e)
  bf16x8 qfrag[2][2];   // [qi][ks]
#pragma unroll
  for (int qi = 0; qi < 2; ++qi) {
    const __bf16* qp = QKV + (size_t)(b * SEQ + M * 128 + qi * 64 + wave * 16 + l16) * NQKV
                     + h * HD + quad * 8;
    bf16x8 q0 = *(const bf16x8*)qp;
    bf16x8 q1 = *(const bf16x8*)(qp + 32);
#pragma unroll
    for (int e = 0; e < 8; ++e) {
      qfrag[qi][0][e] = (__bf16)((float)q0[e] * 0.18033688011112042f);
      qfrag[qi][1][e] = (__bf16)((float)q1[e] * 0.18033688011112042f);
    }
  }

  f32x4 lacc[2] = { {0.f,0.f,0.f,0.f}, {0.f,0.f,0.f,0.f} };
  f32x4 oacc[2][4];
#pragma unroll
  for (int qi = 0; qi < 2; ++qi)
#pragma unroll
    for (int dt = 0; dt < 4; ++dt) oacc[qi][dt] = (f32x4){0.f, 0.f, 0.f, 0.f};

  // prologue: stage tile 0 into buf 0
  {
    const __bf16* kp = Kbase + (size_t)kr * NQKV + kcs;
    gl2lds16(kp,      &Ks[0][0][wave * 512]);
    gl2lds16(kp + 32, &Ks[0][1][wave * 512]);
    const __bf16* vp = VtB + (size_t)vd * SEQ + vsc;
    s16x8 v0 = __builtin_bit_cast(s16x8, *(const bf16x8*)vp);
    s16x8 v1 = __builtin_bit_cast(s16x8, *(const bf16x8*)(vp + 8));
    *(s16x4*)(&Vs[0][(vs4w + 0) * 256 + vcw4]) = __builtin_shufflevector(v0, v0, 0, 1, 2, 3);
    *(s16x4*)(&Vs[0][(vs4w + 1) * 256 + vcw4]) = __builtin_shufflevector(v0, v0, 4, 5, 6, 7);
    *(s16x4*)(&Vs[0][(vs4w + 2) * 256 + vcw4]) = __builtin_shufflevector(v1, v1, 0, 1, 2, 3);
    *(s16x4*)(&Vs[0][(vs4w + 3) * 256 + vcw4]) = __builtin_shufflevector(v1, v1, 4, 5, 6, 7);
  }

  for (int kt = 0; kt < NT; ++kt) {
    int buf = kt & 1;
    __syncthreads();   // prefetch of tile kt drained; buf^1 free to fill

    bool pre = (kt < NT - 1);   // also == "qi0 active" (qi0 needs kt <= 2M)
    s16x8 pv0, pv1;
    if (pre) {
      const __bf16* kp = Kbase + (size_t)((kt + 1) * 64 + kr) * NQKV + kcs;
      gl2lds16(kp,      &Ks[buf ^ 1][0][wave * 512]);
      gl2lds16(kp + 32, &Ks[buf ^ 1][1][wave * 512]);
      const __bf16* vp = VtB + (size_t)vd * SEQ + (kt + 1) * 64 + vsc;
      pv0 = __builtin_bit_cast(s16x8, *(const bf16x8*)vp);
      pv1 = __builtin_bit_cast(s16x8, *(const bf16x8*)(vp + 8));
    }

    // ---- S^T = K Q^T : D[k=quad*4+r][q=l16], both q-halves share kf ----
    f32x4 s0[4], s1[4];
#pragma unroll
    for (int nt = 0; nt < 4; ++nt) {
      s0[nt] = (f32x4){0.f, 0.f, 0.f, 0.f};
      s1[nt] = (f32x4){0.f, 0.f, 0.f, 0.f};
    }
#pragma unroll
    for (int ks = 0; ks < 2; ++ks) {
      bf16x8 kf[4];
#pragma unroll
      for (int nt = 0; nt < 4; ++nt)
        kf[nt] = *(const bf16x8*)(&Ks[buf][ks][(nt * 16 + l16) * 32 + rq]);
#pragma unroll
      for (int nt = 0; nt < 4; ++nt)
        s1[nt] = __builtin_amdgcn_mfma_f32_16x16x32_bf16(kf[nt], qfrag[1][ks], s1[nt], 0, 0, 0);
      if (pre) {
#pragma unroll
        for (int nt = 0; nt < 4; ++nt)
          s0[nt] = __builtin_amdgcn_mfma_f32_16x16x32_bf16(kf[nt], qfrag[0][ks], s0[nt], 0, 0, 0);
      }
    }

    // ---- p = exp2(s^T); pack A-frags for K=16 PV ----
    // qi0 diag at kt == NT-2; qi1 diag at kt == NT-1; else unmasked.
    s16x4 af0[4], af1[4];
    {
      int qg = wave * 16 + l16;
      if (kt == NT - 1) {
#pragma unroll
        for (int nt = 0; nt < 4; ++nt)
#pragma unroll
          for (int rr = 0; rr < 4; ++rr) {
            int kg = nt * 16 + quad * 4 + rr;
            af1[nt][rr] = f2bs(fexp2((kg > qg) ? -1e30f : s1[nt][rr]));
          }
      } else {
#pragma unroll
        for (int nt = 0; nt < 4; ++nt)
#pragma unroll
          for (int rr = 0; rr < 4; ++rr)
            af1[nt][rr] = f2bs(fexp2(s1[nt][rr]));
      }
      if (pre) {
        if (kt == NT - 2) {
#pragma unroll
          for (int nt = 0; nt < 4; ++nt)
#pragma unroll
            for (int rr = 0; rr < 4; ++rr) {
              int kg = nt * 16 + quad * 4 + rr;
              af0[nt][rr] = f2bs(fexp2((kg > qg) ? -1e30f : s0[nt][rr]));
            }
        } else {
#pragma unroll
          for (int nt = 0; nt < 4; ++nt)
#pragma unroll
            for (int rr = 0; rr < 4; ++rr)
              af0[nt][rr] = f2bs(fexp2(s0[nt][rr]));
        }
      }
    }

    // ---- O += P @ V ; row-sum += P @ 1 (both q-halves share vf) ----
    // read swizzle key for s4 = nt*4+quad is (s4>>2)&3 = nt
#pragma unroll
    for (int nt = 0; nt < 4; ++nt) {
      s16x4 vf[4];
#pragma unroll
      for (int dt = 0; dt < 4; ++dt)
        vf[dt] = *(const s16x4*)(&Vs[buf][(nt * 4 + quad) * 256 +
                                          (((dt * 16 + l16) ^ (nt * 4)) * 4)]);
#pragma unroll
      for (int dt = 0; dt < 4; ++dt)
        oacc[1][dt] = mfma16(af1[nt], vf[dt], oacc[1][dt]);
      lacc[1] = mfma16(af1[nt], vones, lacc[1]);
      if (pre) {
#pragma unroll
        for (int dt = 0; dt < 4; ++dt)
          oacc[0][dt] = mfma16(af0[nt], vf[dt], oacc[0][dt]);
        lacc[0] = mfma16(af0[nt], vones, lacc[0]);
      }
    }

    // ---- deferred V ds_write for tile kt+1 (loads had whole tile) ----
    if (pre) {
      *(s16x4*)(&Vs[buf ^ 1][(vs4w + 0) * 256 + vcw4]) = __builtin_shufflevector(pv0, pv0, 0, 1, 2, 3);
      *(s16x4*)(&Vs[buf ^ 1][(vs4w + 1) * 256 + vcw4]) = __builtin_shufflevector(pv0, pv0, 4, 5, 6, 7);
      *(s16x4*)(&Vs[buf ^ 1][(vs4w + 2) * 256 + vcw4]) = __builtin_shufflevector(pv1, pv1, 0, 1, 2, 3);
      *(s16x4*)(&Vs[buf ^ 1][(vs4w + 3) * 256 + vcw4]) = __builtin_shufflevector(pv1, pv1, 4, 5, 6, 7);
    }
  }

  // epilogue: lacc[qi][r] is the full row-sum for q=quad*4+r — same C-layout
  // as oacc, so normalization is lane-local (no shuffles).
#pragma unroll
  for (int qi = 0; qi < 2; ++qi) {
#pragma unroll
    for (int rr = 0; rr < 4; ++rr) {
      float inv = 1.0f / lacc[qi][rr];
#pragma unroll
      for (int dt = 0; dt < 4; ++dt) {
        float o = oacc[qi][dt][rr] * inv;
        O[(size_t)(b * SEQ + M * 128 + qi * 64 + wave * 16 + quad * 4 + rr) * HIDDEN +
          h * HD + dt * 16 + l16] = (__bf16)o;
      }
    }
  }
}

// ---------------------------------------------------------------------------
extern "C" void kernel_launch(void* const* d_in, const int* in_sizes, int n_in,
                              void* d_out, int out_size, void* d_ws, size_t ws_size,
                              hipStream_t stream) {
  const float* x  = (const float*)d_in[0];
  const float* Wq = (const float*)d_in[1];
  const float* Wk = (const float*)d_in[2];
  const float* Wv = (const float*)d_in[3];
  const float* Wo = (const float*)d_in[4];
  const int* pos  = (const int*)d_in[5];

  __bf16* Wqkvt = (__bf16*)d_ws;                       // [5120][2048]: Wqkv^T | Wo^T
  __bf16* Wot   = Wqkvt + (size_t)NQKV * HIDDEN;
  __bf16* Xb    = Wot + (size_t)HIDDEN * HIDDEN;
  __bf16* QKV   = Xb + (size_t)ROWS * HIDDEN;
  __bf16* Oat   = QKV + (size_t)ROWS * NQKV;
  __bf16* Vt    = Xb;   // alias: Xb dead after QKV GEMM

  prep<<<dim3(4608), 256, 0, stream>>>(Wq, Wk, Wv, Wo, x, Wqkvt, Xb);

  gemm_bt<__bf16, true><<<dim3(768), 256, 0, stream>>>(
      Xb, Wqkvt, QKV, ROWS, NQKV, HIDDEN, pos, Vt);

  flash_attn<<<dim3(64, NKVH, BATCH), 256, 0, stream>>>(QKV, Vt, Oat);

  gemm_bt<float, false><<<dim3(512), 256, 0, stream>>>(
      Oat, Wot, (float*)d_out, ROWS, HIDDEN, HIDDEN, nullptr, nullptr);
}